// Round 7
// baseline (81.462 us; speedup 1.0000x reference)
//
#include <hip/hip_runtime.h>

// DensityLoss: B=8, N=4096, radius=0.1, NSAMPLE=9, TOPK=5, H=0.12, EPS=1e-12
// Output: scalar mean over [B,N,TOPK-1] of (RADIUS - sqrt(ds)*exp(-ds/H^2))
//
// R7: grid-binned ball query, restructured from R6:
//  - run-wise candidate iteration (no rs/rp register arrays, no per-candidate
//    position chain) -> VGPR <= 64, 2 blocks/CU (R6 likely tipped past 64).
//  - rank-by-original-index via __shfl broadcast (register-only), replacing
//    R6's dependent LDS-read loop (~17 x 60cyc per query).
//  - binned points packed float4(x,y,z,idx): 1 ds_read_b128 per candidate.
// Semantics exact: qualifiers (same fmaf diff-form predicate) are collected
// from the 27 neighbor cells (superset of ball), ranked by original index;
// slot=rank<9, fill=rank-0 ds == reference's index-sorted ball-query slots.

#define NB 8
#define NPTS 4096
#define NS 9
#define RAD2 0.01f
#define H2 0.0144f
#define EPSV 1e-12f
#define SCALE (1.0f / 131072.0f)   // 1/(B*N*(TOPK-1)) = 1/(8*4096*4)
#define QCAP 64                    // qualifier cap (E=17, uniform input: P(>64)~0)

__global__ __launch_bounds__(1024, 8) void density_loss_kernel(
    const float* __restrict__ pred, float* __restrict__ out) {
    __shared__ __align__(16) float4 sp[NPTS];   // binned (x,y,z,idx-bits) 64KB
    __shared__ int cellStart[1008];   // counts, then in-place exclusive prefix
    __shared__ float qds[16][QCAP];   // per-wave qualifier ds
    __shared__ unsigned short qid[16][QCAP];    // per-wave qualifier orig idx
    __shared__ float buf[64][NS];     // per-point slots (index-rank order)
    __shared__ int cnts[64];
    __shared__ int wtot[16], wtote[16];

    const int tid  = threadIdx.x;
    const int lane = tid & 63;
    const int wid  = tid >> 6;
    const int b    = blockIdx.x >> 6;                        // 64 blocks/batch
    const int nbase = ((blockIdx.x & 63) << 6) + (wid << 2); // 4 queries/wave
    const float* src = pred + (size_t)b * (NPTS * 3);

    if (tid < 1008) cellStart[tid] = 0;
    __syncthreads();

    // ---- Load 4 points/thread (coalesced float4), cell-id, count.
    float px[4], py[4], pz[4];
    int cid[4], off[4];
    {
        const float4* s4 = (const float4*)src;
        float4 A = s4[3 * tid], Bq = s4[3 * tid + 1], Cq = s4[3 * tid + 2];
        px[0] = A.x;  py[0] = A.y;  pz[0] = A.z;
        px[1] = A.w;  py[1] = Bq.x; pz[1] = Bq.y;
        px[2] = Bq.z; py[2] = Bq.w; pz[2] = Cq.x;
        px[3] = Cq.y; py[3] = Cq.z; pz[3] = Cq.w;
        #pragma unroll
        for (int k = 0; k < 4; ++k) {
            int cx = min((int)(px[k] * 10.0f), 9);
            int cy = min((int)(py[k] * 10.0f), 9);
            int cz = min((int)(pz[k] * 10.0f), 9);
            cid[k] = (cx * 10 + cy) * 10 + cz;
            off[k] = atomicAdd(&cellStart[cid[k]], 1);
        }
    }
    __syncthreads();

    // ---- In-place exclusive scan of cellStart (shfl wave scan + wave totals).
    {
        int val = (tid < 1000) ? cellStart[tid] : 0;
        int incl = val;
        #pragma unroll
        for (int o = 1; o < 64; o <<= 1) {
            int t = __shfl_up(incl, o, 64);
            if (lane >= o) incl += t;
        }
        if (lane == 63) wtot[wid] = incl;
        __syncthreads();   // all reads done before in-place writes
        if (wid == 0) {
            int wv = (lane < 16) ? wtot[lane] : 0;
            int wi = wv;
            #pragma unroll
            for (int o = 1; o < 16; o <<= 1) {
                int t = __shfl_up(wi, o, 64);
                if (lane >= o) wi += t;
            }
            if (lane < 16) wtote[lane] = wi - wv;
        }
        __syncthreads();
        if (tid < 1008) cellStart[tid] = wtote[wid] + incl - val;
    }
    __syncthreads();

    // ---- Scatter into binned packed array.
    #pragma unroll
    for (int k = 0; k < 4; ++k) {
        int pos = cellStart[cid[k]] + off[k];
        sp[pos] = (float4){px[k], py[k], pz[k], __int_as_float((tid << 2) + k)};
    }
    __syncthreads();

    // ---- Query phase: 4 queries/wave; 9 z-runs of the 27-cell neighborhood.
    float qxv[4], qyv[4], qzv[4];
    #pragma unroll
    for (int q = 0; q < 4; ++q) {      // hoisted: independent loads, ILP
        int n = nbase + q;
        qxv[q] = src[3 * n]; qyv[q] = src[3 * n + 1]; qzv[q] = src[3 * n + 2];
    }

    for (int q = 0; q < 4; ++q) {
        const float qx = qxv[q], qy = qyv[q], qz = qzv[q];
        const int cx = min((int)(qx * 10.0f), 9);
        const int cy = min((int)(qy * 10.0f), 9);
        const int cz = min((int)(qz * 10.0f), 9);
        const int z0 = max(cz - 1, 0);
        const int zext = min(cz + 1, 9) - z0 + 1;
        int qn = 0;
        #pragma unroll
        for (int u = 0; u < 9; ++u) {
            const int ix = cx + (u / 3) - 1;
            const int iy = cy + (u % 3) - 1;
            if (ix < 0 || ix > 9 || iy < 0 || iy > 9) continue; // wave-uniform
            const int c0 = (ix * 10 + iy) * 10 + z0;
            const int s = cellStart[c0];
            const int len = cellStart[c0 + zext] - s;   // broadcast LDS reads
            for (int base = 0; base < len; base += 64) {  // ~always 1 iter
                const int j = base + lane;
                const bool inb = (j < len);
                float4 c = sp[inb ? (s + j) : s];
                float dx = c.x - qx, dy = c.y - qy, dz = c.z - qz;
                float ds = fmaf(dz, dz, fmaf(dy, dy, dx * dx));
                bool qual = inb && (ds <= RAD2);
                unsigned long long m = __ballot(qual);
                if (m) {
                    if (qual) {
                        unsigned r = __builtin_amdgcn_mbcnt_lo((unsigned)m, 0u);
                        r = __builtin_amdgcn_mbcnt_hi((unsigned)(m >> 32), r);
                        int w = qn + (int)r;
                        if (w < QCAP) {
                            qds[wid][w] = ds;
                            qid[wid][w] = (unsigned short)__float_as_int(c.w);
                        }
                    }
                    qn += (int)__popcll(m);
                }
            }
        }
        // Rank stored qualifiers by original index — register-only (readlane).
        const int qc = qn > QCAP ? QCAP : qn;   // qc >= 1 (self qualifies)
        int myid = (lane < qc) ? (int)qid[wid][lane] : 0x7fffffff;
        float myds = qds[wid][lane < qc ? lane : 0];
        int rank = 0;
        for (int j2 = 0; j2 < qc; ++j2) {
            int o = __shfl(myid, j2, 64);
            rank += (o < myid) ? 1 : 0;
        }
        if (lane < qc && rank < NS) buf[(wid << 2) + q][rank] = myds;
        if (lane == 0) cnts[(wid << 2) + q] = qc < NS ? qc : NS;
    }
    __syncthreads();

    // ---- Epilogue: lane i of wave 0 handles block point i.
    if (tid < 64) {
        int cnt = cnts[tid];
        float s[NS];
        float first = buf[tid][0];   // ds of smallest-index qualifier
        #pragma unroll
        for (int j = 0; j < NS; ++j) {
            float v = buf[tid][j];
            s[j] = (j < cnt) ? v : first;
        }
        #pragma unroll
        for (int i = 0; i < 5; ++i) {   // smallest 5 ascending into s[0..4]
            #pragma unroll
            for (int j = i + 1; j < NS; ++j) {
                float lo = fminf(s[i], s[j]);
                float hi = fmaxf(s[i], s[j]);
                s[i] = lo; s[j] = hi;
            }
        }
        float acc = 0.0f;
        #pragma unroll
        for (int i = 1; i < 5; ++i) {
            float c = (s[i] < EPSV) ? EPSV : s[i];
            acc += 0.1f - sqrtf(c) * expf(-c / H2);
        }
        #pragma unroll
        for (int o = 32; o >= 1; o >>= 1)
            acc += __shfl_down(acc, o, 64);
        if (tid == 0) atomicAdd(out, acc * SCALE);
    }
}

extern "C" void kernel_launch(void* const* d_in, const int* in_sizes, int n_in,
                              void* d_out, int out_size, void* d_ws, size_t ws_size,
                              hipStream_t stream) {
    const float* pred = (const float*)d_in[0];
    float* out = (float*)d_out;
    // d_out is re-poisoned to 0xAA before every timed launch — zero it ourselves.
    hipMemsetAsync(out, 0, sizeof(float), stream);
    density_loss_kernel<<<dim3(NB * 64), dim3(1024), 0, stream>>>(pred, out);
}

// Round 8
// 74.033 us; speedup vs baseline: 1.1004x; 1.1004x over previous
//
#include <hip/hip_runtime.h>

// DensityLoss: B=8, N=4096, radius=0.1, NSAMPLE=9, TOPK=5, H=0.12, EPS=1e-12
// Output: scalar mean over [B,N,TOPK-1] of (RADIUS - sqrt(ds)*exp(-ds/H^2))
//
// R8 = R5's scan (best known, ~26us kernel, absmax 0.0) with the output
// reduction de-contended: R5 ended with 512 near-simultaneous atomicAdds to
// ONE global address (same-cacheline f32 atomics serialize at one L2 bank,
// ~4-10us tail). Now each block plain-stores its partial to ws[blockIdx]
// and a tiny second kernel reduces 512 floats -> out. Also removes the
// out-memset dispatch from the captured graph (k2 writes out directly).

#define NB 8
#define NPTS 4096
#define NS 9
#define RAD2 0.01f
#define H2 0.0144f
#define EPSV 1e-12f
#define SCALE (1.0f / 131072.0f)   // 1/(B*N*(TOPK-1)) = 1/(8*4096*4)

typedef float v2f __attribute__((ext_vector_type(2)));

__device__ __forceinline__ void step(float val, int& cnt, float* row) {
    bool q = (val <= RAD2);
    unsigned long long m = __ballot(q);
    if (m) {                       // wave-uniform -> s_cbranch
        if (q) {                   // exec-masked
            unsigned r = __builtin_amdgcn_mbcnt_lo((unsigned)m, 0u);
            r = __builtin_amdgcn_mbcnt_hi((unsigned)(m >> 32), r);
            int slot = cnt + (int)r;
            if (slot < NS) row[slot] = val;
        }
        cnt += (int)__popcll(m);   // scalar (s_bcnt1)
    }
}

__global__ __launch_bounds__(1024) void density_loss_kernel(
    const float* __restrict__ pred, float* __restrict__ part) {
    __shared__ __align__(16) float sh[3 * NPTS];   // 48 KB transposed SoA
    __shared__ __align__(16) float buf[64][NS];    // per-point neighbor slots
    __shared__ __align__(16) int cnts[64];

    const int tid   = threadIdx.x;
    const int lane  = tid & 63;
    const int wid   = tid >> 6;
    const int b     = blockIdx.x >> 6;                       // 64 blocks/batch
    const int nbase = ((blockIdx.x & 63) << 6) + (wid << 2); // 4 queries/wave

    // ---- Stage: strided global float3 reads -> contiguous b128 LDS writes.
    // Block-transposed SoA: candidate c at (c & ~255) + ((c&63)<<2) + ((c>>6)&3)
    // per plane; lane L's float4 in block g = candidates {g*256+L,+64,+128,+192}.
    {
        const float* src = pred + (size_t)b * (NPTS * 3);
        const int cbase = (wid << 8) + lane;
        float xs[4], ys[4], zs[4];
        #pragma unroll
        for (int k = 0; k < 4; ++k) {
            const float* p = src + 3 * (cbase + (k << 6));
            xs[k] = p[0]; ys[k] = p[1]; zs[k] = p[2];
        }
        *(float4*)(sh + (tid << 2))            = (float4){xs[0], xs[1], xs[2], xs[3]};
        *(float4*)(sh + NPTS + (tid << 2))     = (float4){ys[0], ys[1], ys[2], ys[3]};
        *(float4*)(sh + 2 * NPTS + (tid << 2)) = (float4){zs[0], zs[1], zs[2], zs[3]};
    }
    __syncthreads();

    // Query coords (wave-uniform -> scalarizable)
    float qx[4], qy[4], qz[4];
    #pragma unroll
    for (int q = 0; q < 4; ++q) {
        int n = nbase + q;
        int p = (n & ~255) | ((n & 63) << 2) | ((n >> 6) & 3);
        qx[q] = sh[p]; qy[q] = sh[NPTS + p]; qz[q] = sh[2 * NPTS + p];
    }

    // ---- Scan: 256 candidates/iteration via 3x ds_read_b128, shared
    // across the wave's 4 query points. Sub-chunks k=0..3 in index order;
    // per-point early-skip and wave early-exit.
    int c0 = 0, c1 = 0, c2 = 0, c3 = 0;
    const float* pl = sh + (lane << 2);
    for (int g = 0; g < NPTS / 256; ++g, pl += 256) {
        float4 xa = *(const float4*)pl;
        float4 ya = *(const float4*)(pl + NPTS);
        float4 za = *(const float4*)(pl + 2 * NPTS);
        v2f xl = {xa.x, xa.y}, xh = {xa.z, xa.w};
        v2f yl = {ya.x, ya.y}, yh = {ya.z, ya.w};
        v2f zl = {za.x, za.y}, zh = {za.z, za.w};
        #pragma unroll
        for (int q = 0; q < 4; ++q) {
            int& cq = (q == 0) ? c0 : (q == 1) ? c1 : (q == 2) ? c2 : c3;
            if (cq >= NS) continue;          // wave-uniform skip (point done)
            v2f px = {qx[q], qx[q]}, py = {qy[q], qy[q]}, pz = {qz[q], qz[q]};
            v2f dxl = xl - px, dyl = yl - py, dzl = zl - pz;
            v2f dxh = xh - px, dyh = yh - py, dzh = zh - pz;
            v2f dl = dxl * dxl + dyl * dyl + dzl * dzl;
            v2f dh = dxh * dxh + dyh * dyh + dzh * dzh;
            float* row = buf[(wid << 2) + q];
            step(dl.x, cq, row);
            step(dl.y, cq, row);
            step(dh.x, cq, row);
            step(dh.y, cq, row);
        }
        if (c0 >= NS && c1 >= NS && c2 >= NS && c3 >= NS) break;
    }
    if (lane == 0)
        *(int4*)(cnts + (wid << 2)) = (int4){c0, c1, c2, c3};
    __syncthreads();

    // ---- Epilogue: lane i of wave 0 handles block point i.
    if (tid < 64) {
        int cnt = cnts[tid]; if (cnt > NS) cnt = NS;   // cnt >= 1 (self)
        float s[NS];
        float first = buf[tid][0];
        #pragma unroll
        for (int j = 0; j < NS; ++j) {
            float v = buf[tid][j];
            s[j] = (j < cnt) ? v : first;
        }
        // Partial selection sort: smallest 5 ascending into s[0..4]
        #pragma unroll
        for (int i = 0; i < 5; ++i) {
            #pragma unroll
            for (int j = i + 1; j < NS; ++j) {
                float lo = fminf(s[i], s[j]);
                float hi = fmaxf(s[i], s[j]);
                s[i] = lo; s[j] = hi;
            }
        }
        float acc = 0.0f;
        #pragma unroll
        for (int i = 1; i < 5; ++i) {
            float c = (s[i] < EPSV) ? EPSV : s[i];
            acc += 0.1f - sqrtf(c) * expf(-c / H2);
        }
        #pragma unroll
        for (int off = 32; off >= 1; off >>= 1)
            acc += __shfl_down(acc, off, 64);
        // Plain store — no atomic contention; all 512 slots written.
        if (tid == 0) part[blockIdx.x] = acc;
    }
}

__global__ __launch_bounds__(512) void reduce_kernel(
    const float* __restrict__ part, float* __restrict__ out) {
    __shared__ float w[8];
    const int tid = threadIdx.x;
    float s = part[tid];               // 512 partials, 512 threads
    #pragma unroll
    for (int o = 32; o >= 1; o >>= 1)
        s += __shfl_down(s, o, 64);
    if ((tid & 63) == 0) w[tid >> 6] = s;
    __syncthreads();
    if (tid == 0) {
        float t = 0.0f;
        #pragma unroll
        for (int i = 0; i < 8; ++i) t += w[i];
        out[0] = t * SCALE;            // out poisoned each launch; full write
    }
}

extern "C" void kernel_launch(void* const* d_in, const int* in_sizes, int n_in,
                              void* d_out, int out_size, void* d_ws, size_t ws_size,
                              hipStream_t stream) {
    const float* pred = (const float*)d_in[0];
    float* out = (float*)d_out;
    float* part = (float*)d_ws;        // 512 floats of the 256MB workspace
    density_loss_kernel<<<dim3(NB * 64), dim3(1024), 0, stream>>>(pred, part);
    reduce_kernel<<<dim3(1), dim3(512), 0, stream>>>(part, out);
}